// Round 11
// baseline (4875.166 us; speedup 1.0000x reference)
//
#include <hip/hip_runtime.h>
#include <math.h>

#define NND 100000      // nodes per phi
#define NE  1250000     // edges
#define NN2 200000      // 2N (pos+neg batched)
#define BNE 1e-5f

typedef unsigned long long u64;

// ---------------- workspace layout (float offsets) ----------------
// seq is live for the whole pipeline. Union U (38.4M floats):
//   conv : agg = U+0 (12.8M)  tmp1 = U+12.8M (12.8M)  CSR ints = U+25.6M (~1.45M)
//   lstm : hL  = U+0 (19.2M)  cL   = U+19.2M (19.2M)
//   jk   : jkout=U+0 (12.8M)  tmp2 = U+12.8M (12.8M)  phi = U+25.6M (6.4M)
#define OFF_SEQ   0ull                    // 3 * NN2 * 64 = 38,400,000
#define OFF_U     38400000ull             // union: 38,400,000 floats
#define OFF_ALPHA 76800000ull             // 3 * NN2 = 600,000
#define OFF_STATS 77400000ull             // 512
#define OFF_BF    77400512ull             // 160*384
#define OFF_BB    77461952ull             // 160*384
#define OFF_BBF   77523392ull             // 384
#define OFF_BBB   77523776ull             // 384
#define WS_FLOATS 77524160ull             // ~310.1 MB

__device__ __forceinline__ float fsig(float x)  { return 1.f/(1.f + __expf(-x)); }
__device__ __forceinline__ float ftanh(float x) { return 1.f - 2.f/(__expf(2.f*x) + 1.f); }

__device__ __forceinline__ void fma16(float (&acc)[4][4], const float4 a, const float4 b) {
  acc[0][0]=fmaf(a.x,b.x,acc[0][0]); acc[0][1]=fmaf(a.x,b.y,acc[0][1]);
  acc[0][2]=fmaf(a.x,b.z,acc[0][2]); acc[0][3]=fmaf(a.x,b.w,acc[0][3]);
  acc[1][0]=fmaf(a.y,b.x,acc[1][0]); acc[1][1]=fmaf(a.y,b.y,acc[1][1]);
  acc[1][2]=fmaf(a.y,b.z,acc[1][2]); acc[1][3]=fmaf(a.y,b.w,acc[1][3]);
  acc[2][0]=fmaf(a.z,b.x,acc[2][0]); acc[2][1]=fmaf(a.z,b.y,acc[2][1]);
  acc[2][2]=fmaf(a.z,b.z,acc[2][2]); acc[2][3]=fmaf(a.z,b.w,acc[2][3]);
  acc[3][0]=fmaf(a.w,b.x,acc[3][0]); acc[3][1]=fmaf(a.w,b.y,acc[3][1]);
  acc[3][2]=fmaf(a.w,b.z,acc[3][2]); acc[3][3]=fmaf(a.w,b.w,acc[3][3]);
}

// ================= CSR build (dst -> edge list), once per call =================
__global__ void hist_kernel(const int* __restrict__ dstp, int* __restrict__ cnt) {
  int e = blockIdx.x*256 + threadIdx.x;
  if (e < NE) atomicAdd(&cnt[dstp[e]], 1);
}

#define SCAN_B 1024
__global__ void scan1_kernel(const int* __restrict__ cnt, int* __restrict__ ofs,
                             int* __restrict__ bsum, int n) {
  __shared__ int lds[SCAN_B];
  int tid = threadIdx.x;
  int gid = blockIdx.x*SCAN_B + tid;
  int v = (gid < n) ? cnt[gid] : 0;
  lds[tid] = v;
  __syncthreads();
  for (int s = 1; s < SCAN_B; s <<= 1) {
    int t = (tid >= s) ? lds[tid - s] : 0;
    __syncthreads();
    lds[tid] += t;
    __syncthreads();
  }
  if (gid < n) ofs[gid] = lds[tid] - v;
  if (tid == SCAN_B-1) bsum[blockIdx.x] = lds[tid];
}

__global__ void scan2_kernel(int* __restrict__ bsum, int nb) {
  __shared__ int lds[128];
  int tid = threadIdx.x;
  int v = (tid < nb) ? bsum[tid] : 0;
  lds[tid] = v;
  __syncthreads();
  for (int s = 1; s < 128; s <<= 1) {
    int t = (tid >= s) ? lds[tid - s] : 0;
    __syncthreads();
    lds[tid] += t;
    __syncthreads();
  }
  if (tid < nb) bsum[tid] = lds[tid] - v;
}

__global__ void scan3_kernel(int* __restrict__ ofs, const int* __restrict__ bsum,
                             int* __restrict__ cur, int n) {
  int gid = blockIdx.x*SCAN_B + threadIdx.x;
  if (gid < n) {
    int o = ofs[gid] + bsum[blockIdx.x];
    ofs[gid] = o;
    cur[gid] = o;
  }
  if (gid == 0) ofs[n] = NE;
}

__global__ void fill_kernel(const int* __restrict__ dstp, int* __restrict__ cur,
                            int* __restrict__ eidl) {
  int e = blockIdx.x*256 + threadIdx.x;
  if (e < NE) {
    int p = atomicAdd(&cur[dstp[e]], 1);
    eidl[p] = e;
  }
}

// ========== gather aggregation: agg[n] = sum_{e: dst=n} relu(h[src]+emb(e)) ==========
template<int C, bool L0>
__global__ __launch_bounds__(256) void gather_kernel(
    const float* __restrict__ ea, const int* __restrict__ srcp,
    const int* __restrict__ ofs, const int* __restrict__ eidl,
    const float* __restrict__ lew, const float* __restrict__ leb,
    const float* __restrict__ hin, float* __restrict__ agg)
{
  __shared__ float sW[17*C];
  for (int i = threadIdx.x; i < 17*C; i += 256)
    sW[i] = (i < 16*C) ? lew[i] : leb[i - 16*C];
  __syncthreads();
  int lane = threadIdx.x & (C - 1);
  int grp  = threadIdx.x / C;
  int node = blockIdx.x*(256/C) + grp;
  if (node >= NND) return;
  int st = ofs[node], en = ofs[node+1];
  float accp = 0.f, accn = 0.f;
  int eid = 0, s = 0;
  if (st < en) { eid = eidl[st]; s = srcp[eid]; }
  for (int i = st; i < en; i++) {
    int neid = 0, ns = 0;
    if (i + 1 < en) { neid = eidl[i+1]; ns = srcp[neid]; }
    const float4* ea4 = reinterpret_cast<const float4*>(ea + (u64)eid*16);
    float emb = sW[16*C + lane];
    #pragma unroll
    for (int k4 = 0; k4 < 4; k4++) {
      float4 v = ea4[k4];
      emb = fmaf(v.x, sW[(4*k4+0)*C+lane], emb);
      emb = fmaf(v.y, sW[(4*k4+1)*C+lane], emb);
      emb = fmaf(v.z, sW[(4*k4+2)*C+lane], emb);
      emb = fmaf(v.w, sW[(4*k4+3)*C+lane], emb);
    }
    float hp, hn;
    if (L0) { hp = hin[(u64)s*C + lane]; hn = -hp; }
    else    { hp = hin[(u64)s*C + lane]; hn = hin[(u64)(NND + s)*C + lane]; }
    accp += fmaxf(hp + emb, 0.f);
    accn += fmaxf(hn + emb, 0.f);
    eid = neid; s = ns;
  }
  agg[(u64)node*C + lane]        = accp;
  agg[(u64)(NND + node)*C + lane] = accn;
}

// ------------- node GEMM 1: tmp1 = (agg + (1+eps)h) @ W + b ; optional BN partial stats ----
template<int CIN, int MODE, bool STATS>
__global__ __launch_bounds__(256) void node1_kernel(
    const float* __restrict__ agg, const float* __restrict__ hin,
    const float* __restrict__ epsp, int layer,
    const float* __restrict__ W, const float* __restrict__ bias,
    float* __restrict__ outp, float* __restrict__ stats, int rps)
{
  __shared__ __align__(16) float At[CIN][68];
  __shared__ __align__(16) float Bs[CIN][64];
  __shared__ float red[16][64];
  int tid = threadIdx.x;
  int sgn = blockIdx.y;
  int rowbase = blockIdx.x*64;
  for (int i = tid; i < CIN*64; i += 256) Bs[i>>6][i&63] = W[i];
  float sc = 1.f;
  if (MODE < 2) sc = 1.f + epsp[layer];
  for (int i = tid; i < 64*CIN; i += 256) {
    int r = i / CIN, k = i % CIN;
    int row = rowbase + r;
    float v = 0.f;
    if (row < rps) {
      int grow = sgn*rps + row;
      if (MODE == 0)      { float xv = hin[(u64)row*CIN + k]; v = agg[(u64)grow*CIN + k] + sc*(sgn ? -xv : xv); }
      else if (MODE == 1) { v = agg[(u64)grow*CIN + k] + sc*hin[(u64)grow*CIN + k]; }
      else                { v = hin[(u64)grow*64 + k]; }
    }
    At[k][r] = v;
  }
  __syncthreads();
  int rg = tid >> 4, cg = tid & 15;
  float acc[4][4] = {};
  // unroll capped: full unroll spilled (VGPR=256, scratch-bound, r2 post-mortem)
  #pragma unroll 4
  for (int k = 0; k < CIN; k++) {
    float4 a = *reinterpret_cast<const float4*>(&At[k][rg*4]);
    float4 b = *reinterpret_cast<const float4*>(&Bs[k][cg*4]);
    fma16(acc, a, b);
  }
  float bv[4];
  #pragma unroll
  for (int c = 0; c < 4; c++) bv[c] = bias[cg*4 + c];
  #pragma unroll
  for (int i = 0; i < 4; i++) {
    int row = rowbase + rg*4 + i;
    if (row < rps) {
      int grow = sgn*rps + row;
      float4 o4 = make_float4(acc[i][0]+bv[0], acc[i][1]+bv[1], acc[i][2]+bv[2], acc[i][3]+bv[3]);
      *reinterpret_cast<float4*>(&outp[(u64)grow*64 + cg*4]) = o4;
    }
  }
  if constexpr (STATS) {
    float sm[4] = {0,0,0,0}, sq[4] = {0,0,0,0};
    #pragma unroll
    for (int i = 0; i < 4; i++) {
      int row = rowbase + rg*4 + i;
      if (row < rps) {
        #pragma unroll
        for (int c = 0; c < 4; c++) { float t = acc[i][c] + bv[c]; sm[c] += t; sq[c] += t*t; }
      }
    }
    __syncthreads();
    #pragma unroll
    for (int c = 0; c < 4; c++) red[rg][cg*4+c] = sm[c];
    __syncthreads();
    for (int st = 8; st >= 1; st >>= 1) {
      if (rg < st) {
        #pragma unroll
        for (int c = 0; c < 4; c++) red[rg][cg*4+c] += red[rg+st][cg*4+c];
      }
      __syncthreads();
    }
    if (rg == 0) {
      #pragma unroll
      for (int c = 0; c < 4; c++) atomicAdd(&stats[sgn*64 + cg*4 + c], red[0][cg*4+c]);
    }
    __syncthreads();
    #pragma unroll
    for (int c = 0; c < 4; c++) red[rg][cg*4+c] = sq[c];
    __syncthreads();
    for (int st = 8; st >= 1; st >>= 1) {
      if (rg < st) {
        #pragma unroll
        for (int c = 0; c < 4; c++) red[rg][cg*4+c] += red[rg+st][cg*4+c];
      }
      __syncthreads();
    }
    if (rg == 0) {
      #pragma unroll
      for (int c = 0; c < 4; c++) atomicAdd(&stats[128 + sgn*64 + cg*4 + c], red[0][cg*4+c]);
    }
  }
}

__global__ void bn_finalize(float* stats, int nsign, float invN) {
  int i = threadIdx.x;
  if (i < nsign*64) {
    float mean = stats[i]*invN;
    float var  = stats[128+i]*invN - mean*mean;
    stats[256+i] = mean;
    stats[384+i] = rsqrtf(fmaxf(var, 0.f) + BNE);
  }
}

// ------------- node GEMM 2: out = [relu]( relu(bn(tmp1)) @ W + b ) -------------
template<bool TRELU>
__global__ __launch_bounds__(256) void node2_kernel(
    const float* __restrict__ tin, const float* __restrict__ stats,
    const float* __restrict__ gam, const float* __restrict__ bet,
    const float* __restrict__ W, const float* __restrict__ bias,
    float* __restrict__ outp, int rps)
{
  __shared__ __align__(16) float At[64][68];
  __shared__ __align__(16) float Bs[64][64];
  __shared__ float scs[64], shs[64];
  int tid = threadIdx.x;
  int sgn = blockIdx.y;
  int rowbase = blockIdx.x*64;
  if (tid < 64) {
    float mean = stats[256 + sgn*64 + tid];
    float istd = stats[384 + sgn*64 + tid];
    float s = istd * gam[tid];
    scs[tid] = s;
    shs[tid] = bet[tid] - mean*s;
  }
  for (int i = tid; i < 64*64; i += 256) Bs[i>>6][i&63] = W[i];
  __syncthreads();
  for (int i = tid; i < 64*64; i += 256) {
    int r = i >> 6, k = i & 63;
    int row = rowbase + r;
    float v = 0.f;
    if (row < rps) {
      int grow = sgn*rps + row;
      v = fmaxf(fmaf(tin[(u64)grow*64 + k], scs[k], shs[k]), 0.f);
    }
    At[k][r] = v;
  }
  __syncthreads();
  int rg = tid >> 4, cg = tid & 15;
  float acc[4][4] = {};
  #pragma unroll 4
  for (int k = 0; k < 64; k++) {
    float4 a = *reinterpret_cast<const float4*>(&At[k][rg*4]);
    float4 b = *reinterpret_cast<const float4*>(&Bs[k][cg*4]);
    fma16(acc, a, b);
  }
  #pragma unroll
  for (int i = 0; i < 4; i++) {
    int row = rowbase + rg*4 + i;
    if (row < rps) {
      int grow = sgn*rps + row;
      float o0 = acc[i][0] + bias[cg*4+0];
      float o1 = acc[i][1] + bias[cg*4+1];
      float o2 = acc[i][2] + bias[cg*4+2];
      float o3 = acc[i][3] + bias[cg*4+3];
      if (TRELU) { o0=fmaxf(o0,0.f); o1=fmaxf(o1,0.f); o2=fmaxf(o2,0.f); o3=fmaxf(o3,0.f); }
      *reinterpret_cast<float4*>(&outp[(u64)grow*64 + cg*4]) = make_float4(o0,o1,o2,o3);
    }
  }
}

// ------------- LSTM weight prep: B[k][u*4+g] = W[g*96+u][k] (gate-interleaved) -------------
__global__ void prep_lstm_w(
    const float* __restrict__ wif, const float* __restrict__ whf,
    const float* __restrict__ bif, const float* __restrict__ bhf,
    const float* __restrict__ wib, const float* __restrict__ whb,
    const float* __restrict__ bib, const float* __restrict__ bhb,
    float* __restrict__ Bf, float* __restrict__ Bb,
    float* __restrict__ bbf, float* __restrict__ bbb)
{
  int idx = blockIdx.x*256 + threadIdx.x;
  if (idx >= 2*160*384) return;
  int d = idx / (160*384);
  int rem = idx - d*160*384;
  int k = rem / 384, ju = rem - k*384;
  int u = ju >> 2, g = ju & 3;
  int grow = g*96 + u;              // torch gate order i,f,g,o
  const float* wi = d ? wib : wif;
  const float* wh = d ? whb : whf;
  float* Bo = d ? Bb : Bf;
  Bo[rem] = (k < 64) ? wi[grow*64 + k] : wh[grow*96 + (k - 64)];
  if (k == 0) {
    const float* bi = d ? bib : bif;
    const float* bh = d ? bhb : bhf;
    (d ? bbb : bbf)[ju] = bi[grow] + bh[grow];
  }
}

// ------------- fused LSTM step: gates GEMM (B read direct from L2) + activations + alpha ----
// r11 change vs r7: drop the per-chunk Bs LDS staging (24.5KB + 20 barriers). B is 245KB,
// L2-resident, read coalesced. LDS = At only (23KB; 9KB when FIRST) -> occupancy 33%->~50%.
template<bool FIRST, bool ACC_ALPHA>
__global__ __launch_bounds__(256) void lstm_step(
    const float* __restrict__ xt, float* __restrict__ h, float* __restrict__ c,
    const float* __restrict__ B, const float* __restrict__ bb,
    const float* __restrict__ attw, float* __restrict__ alpha)
{
  constexpr int K = FIRST ? 64 : 160;
  __shared__ __align__(16) float At[K][36];
  int tid = threadIdx.x;
  int rowbase = blockIdx.x * 32;
  // division-free float4 staging: 8 threads per row
  {
    int r = tid >> 3, t8 = tid & 7;
    u64 grow = (u64)(rowbase + r);
    float4 v0 = *reinterpret_cast<const float4*>(&xt[grow*64 + t8*8]);
    float4 v1 = *reinterpret_cast<const float4*>(&xt[grow*64 + t8*8 + 4]);
    int kx = t8*8;
    At[kx+0][r] = v0.x; At[kx+1][r] = v0.y; At[kx+2][r] = v0.z; At[kx+3][r] = v0.w;
    At[kx+4][r] = v1.x; At[kx+5][r] = v1.y; At[kx+6][r] = v1.z; At[kx+7][r] = v1.w;
    if (!FIRST) {
      float4 h0 = *reinterpret_cast<const float4*>(&h[grow*96 + t8*12]);
      float4 h1 = *reinterpret_cast<const float4*>(&h[grow*96 + t8*12 + 4]);
      float4 h2 = *reinterpret_cast<const float4*>(&h[grow*96 + t8*12 + 8]);
      int kh = 64 + t8*12;
      At[kh+0][r] = h0.x; At[kh+1][r]  = h0.y; At[kh+2][r]  = h0.z; At[kh+3][r]  = h0.w;
      At[kh+4][r] = h1.x; At[kh+5][r]  = h1.y; At[kh+6][r]  = h1.z; At[kh+7][r]  = h1.w;
      At[kh+8][r] = h2.x; At[kh+9][r]  = h2.y; At[kh+10][r] = h2.z; At[kh+11][r] = h2.w;
    }
  }
  __syncthreads();
  float acc[4][3][4] = {};
  int rg = tid >> 5, tc = tid & 31;
  // unroll capped: avoid VGPR spill (r2 post-mortem); B rows hit L1/L2 (245KB, shared by all blocks)
  #pragma unroll 2
  for (int k = 0; k < K; k++) {
    float4 a = *reinterpret_cast<const float4*>(&At[k][rg*4]);
    const float* Brow = B + (u64)k*384 + tc*4;
    #pragma unroll
    for (int uu = 0; uu < 3; uu++) {
      float4 b = *reinterpret_cast<const float4*>(Brow + uu*128);
      acc[0][uu][0]=fmaf(a.x,b.x,acc[0][uu][0]); acc[0][uu][1]=fmaf(a.x,b.y,acc[0][uu][1]);
      acc[0][uu][2]=fmaf(a.x,b.z,acc[0][uu][2]); acc[0][uu][3]=fmaf(a.x,b.w,acc[0][uu][3]);
      acc[1][uu][0]=fmaf(a.y,b.x,acc[1][uu][0]); acc[1][uu][1]=fmaf(a.y,b.y,acc[1][uu][1]);
      acc[1][uu][2]=fmaf(a.y,b.z,acc[1][uu][2]); acc[1][uu][3]=fmaf(a.y,b.w,acc[1][uu][3]);
      acc[2][uu][0]=fmaf(a.z,b.x,acc[2][uu][0]); acc[2][uu][1]=fmaf(a.z,b.y,acc[2][uu][1]);
      acc[2][uu][2]=fmaf(a.z,b.z,acc[2][uu][2]); acc[2][uu][3]=fmaf(a.z,b.w,acc[2][uu][3]);
      acc[3][uu][0]=fmaf(a.w,b.x,acc[3][uu][0]); acc[3][uu][1]=fmaf(a.w,b.y,acc[3][uu][1]);
      acc[3][uu][2]=fmaf(a.w,b.z,acc[3][uu][2]); acc[3][uu][3]=fmaf(a.w,b.w,acc[3][uu][3]);
    }
  }
  float aw[3], bbv[3][4];
  #pragma unroll
  for (int uu = 0; uu < 3; uu++) {
    int u = uu*32 + tc;
    aw[uu] = attw[u];
    #pragma unroll
    for (int g2 = 0; g2 < 4; g2++) bbv[uu][g2] = bb[u*4 + g2];
  }
  float apart[4];
  #pragma unroll
  for (int r = 0; r < 4; r++) {
    int row = rowbase + rg*4 + r;
    float ap = 0.f;
    #pragma unroll
    for (int uu = 0; uu < 3; uu++) {
      int u = uu*32 + tc;
      float gi = acc[r][uu][0] + bbv[uu][0];
      float gf = acc[r][uu][1] + bbv[uu][1];
      float gg = acc[r][uu][2] + bbv[uu][2];
      float go = acc[r][uu][3] + bbv[uu][3];
      float si = fsig(gi);
      float sf = fsig(gf);
      float so = fsig(go);
      float tg = ftanh(gg);
      float cp = FIRST ? 0.f : c[(u64)row*96 + u];
      float cn = fmaf(sf, cp, si*tg);
      float hn = so * ftanh(cn);
      c[(u64)row*96 + u] = cn;
      h[(u64)row*96 + u] = hn;
      ap = fmaf(hn, aw[uu], ap);
    }
    apart[r] = ap;
  }
  #pragma unroll
  for (int m = 16; m >= 1; m >>= 1) {
    #pragma unroll
    for (int r = 0; r < 4; r++) apart[r] += __shfl_xor(apart[r], m, 32);
  }
  if (tc == 0) {
    #pragma unroll
    for (int r = 0; r < 4; r++) {
      int row = rowbase + rg*4 + r;
      float v = apart[r];
      if (ACC_ALPHA) v += alpha[row];
      alpha[row] = v;
    }
  }
}

__global__ void alpha_softmax(float* alpha, const float* __restrict__ attb) {
  int row = blockIdx.x*256 + threadIdx.x;
  if (row >= NN2) return;
  float b = attb[0];
  float a0 = alpha[row] + b, a1 = alpha[NN2+row] + b, a2 = alpha[2*NN2+row] + b;
  float m = fmaxf(a0, fmaxf(a1, a2));
  float e0 = expf(a0-m), e1 = expf(a1-m), e2 = expf(a2-m);
  float inv = 1.f/(e0+e1+e2);
  alpha[row] = e0*inv; alpha[NN2+row] = e1*inv; alpha[2*NN2+row] = e2*inv;
}

__global__ void jk_kernel(const float* __restrict__ alpha, const float* __restrict__ seq,
                          float* __restrict__ outp) {
  int idx = blockIdx.x*256 + threadIdx.x;   // NN2*16
  if (idx >= NN2*16) return;
  int row = idx >> 4, c4 = idx & 15;
  float a0 = alpha[row], a1 = alpha[NN2+row], a2 = alpha[2*NN2+row];
  float4 s0 = *reinterpret_cast<const float4*>(&seq[((u64)0*NN2 + row)*64 + c4*4]);
  float4 s1 = *reinterpret_cast<const float4*>(&seq[((u64)1*NN2 + row)*64 + c4*4]);
  float4 s2 = *reinterpret_cast<const float4*>(&seq[((u64)2*NN2 + row)*64 + c4*4]);
  float4 o;
  o.x = a0*s0.x + a1*s1.x + a2*s2.x;
  o.y = a0*s0.y + a1*s1.y + a2*s2.y;
  o.z = a0*s0.z + a1*s1.z + a2*s2.z;
  o.w = a0*s0.w + a1*s1.w + a2*s2.w;
  *reinterpret_cast<float4*>(&outp[(u64)row*64 + c4*4]) = o;
}

__global__ void phi_sum(const float* __restrict__ t, float* __restrict__ o) {
  int idx = blockIdx.x*256 + threadIdx.x;   // NND*16
  if (idx >= NND*16) return;
  float4 a = reinterpret_cast<const float4*>(t)[idx];
  float4 b = reinterpret_cast<const float4*>(t + (u64)NND*64)[idx];
  reinterpret_cast<float4*>(o)[idx] = make_float4(a.x+b.x, a.y+b.y, a.z+b.z, a.w+b.w);
}

extern "C" void kernel_launch(void* const* d_in, const int* in_sizes, int n_in,
                              void* d_out, int out_size, void* d_ws, size_t ws_size,
                              hipStream_t stream) {
  const float* x    = (const float*)d_in[0];
  const int*   ei   = (const int*)d_in[1];
  const int*   srcp = ei;
  const int*   dstp = ei + NE;
  const float* ea   = (const float*)d_in[2];
  const float* lew[3] = {(const float*)d_in[3],  (const float*)d_in[11], (const float*)d_in[19]};
  const float* leb[3] = {(const float*)d_in[4],  (const float*)d_in[12], (const float*)d_in[20]};
  const float* w1[3]  = {(const float*)d_in[5],  (const float*)d_in[13], (const float*)d_in[21]};
  const float* b1[3]  = {(const float*)d_in[6],  (const float*)d_in[14], (const float*)d_in[22]};
  const float* gg[3]  = {(const float*)d_in[7],  (const float*)d_in[15], (const float*)d_in[23]};
  const float* be[3]  = {(const float*)d_in[8],  (const float*)d_in[16], (const float*)d_in[24]};
  const float* w2[3]  = {(const float*)d_in[9],  (const float*)d_in[17], (const float*)d_in[25]};
  const float* b2[3]  = {(const float*)d_in[10], (const float*)d_in[18], (const float*)d_in[26]};
  const float* eps  = (const float*)d_in[27];
  const float* wif  = (const float*)d_in[28];
  const float* whf  = (const float*)d_in[29];
  const float* bif  = (const float*)d_in[30];
  const float* bhf  = (const float*)d_in[31];
  const float* wib  = (const float*)d_in[32];
  const float* whb  = (const float*)d_in[33];
  const float* bib  = (const float*)d_in[34];
  const float* bhb  = (const float*)d_in[35];
  const float* attw = (const float*)d_in[36];
  const float* attb = (const float*)d_in[37];
  const float* jkw  = (const float*)d_in[38];
  const float* jkb  = (const float*)d_in[39];
  const float* rw1  = (const float*)d_in[40];
  const float* rb1  = (const float*)d_in[41];
  const float* rg_  = (const float*)d_in[42];
  const float* rbe  = (const float*)d_in[43];
  const float* rw2  = (const float*)d_in[44];
  const float* rb2  = (const float*)d_in[45];

  float* ws    = (float*)d_ws;
  float* seq   = ws + OFF_SEQ;
  float* U     = ws + OFF_U;
  float* agg   = U;                       // conv phase
  float* tmp1  = U + 12800000ull;         // conv phase
  float* hL    = U;                       // lstm phase
  float* cL    = U + 19200000ull;         // lstm phase
  float* jkout = U;                       // jk phase
  float* tmp2  = U + 12800000ull;         // jk phase
  float* phi   = U + 25600000ull;         // jk phase (NND*64)
  int* csr_ofs  = (int*)(U + 25600000ull);          // conv phase: NND+1
  int* csr_cur  = csr_ofs + (NND + 1);              // NND
  int* csr_bsum = csr_cur + NND;                    // 128
  int* csr_eidl = csr_bsum + 128;                   // NE
  float* alpha = ws + OFF_ALPHA;
  float* stats = ws + OFF_STATS;
  float* Bf    = ws + OFF_BF;
  float* Bb    = ws + OFF_BB;
  float* bbf   = ws + OFF_BBF;
  float* bbb   = ws + OFF_BBB;
  float* outp  = (float*)d_out;

  if (ws_size < WS_FLOATS * sizeof(float)) return;  // need ~310 MB scratch

  prep_lstm_w<<<480, 256, 0, stream>>>(wif, whf, bif, bhf, wib, whb, bib, bhb, Bf, Bb, bbf, bbb);

  // ---- build CSR (dst -> edges), once per call ----
  const int nscan = (NND + SCAN_B - 1) / SCAN_B;    // 98
  hipMemsetAsync(csr_cur, 0, NND*sizeof(int), stream);
  hist_kernel<<<(NE+255)/256, 256, 0, stream>>>(dstp, csr_cur);
  scan1_kernel<<<nscan, SCAN_B, 0, stream>>>(csr_cur, csr_ofs, csr_bsum, NND);
  scan2_kernel<<<1, 128, 0, stream>>>(csr_bsum, nscan);
  scan3_kernel<<<nscan, SCAN_B, 0, stream>>>(csr_ofs, csr_bsum, csr_cur, NND);
  fill_kernel<<<(NE+255)/256, 256, 0, stream>>>(dstp, csr_cur, csr_eidl);

  // ---- 3 GINE layers, both signs batched (2N rows), gather aggregation ----
  for (int l = 0; l < 3; l++) {
    const float* hin = (l == 0) ? x : (seq + (u64)(l-1)*NN2*64);
    if (l == 0)
      gather_kernel<16, true ><<<(NND+15)/16, 256, 0, stream>>>(ea, srcp, csr_ofs, csr_eidl,
                                                                lew[l], leb[l], hin, agg);
    else
      gather_kernel<64, false><<<(NND+3)/4, 256, 0, stream>>>(ea, srcp, csr_ofs, csr_eidl,
                                                              lew[l], leb[l], hin, agg);
    hipMemsetAsync(stats, 0, 256*sizeof(float), stream);
    dim3 g1(1563, 2);
    if (l == 0)
      node1_kernel<16, 0, true><<<g1, 256, 0, stream>>>(agg, x, eps, l, w1[l], b1[l], tmp1, stats, NND);
    else
      node1_kernel<64, 1, true><<<g1, 256, 0, stream>>>(agg, hin, eps, l, w1[l], b1[l], tmp1, stats, NND);
    bn_finalize<<<1, 128, 0, stream>>>(stats, 2, 1.0f/NND);
    node2_kernel<true><<<g1, 256, 0, stream>>>(tmp1, stats, gg[l], be[l], w2[l], b2[l],
                                               seq + (u64)l*NN2*64, NND);
  }

  // ---- BiLSTM over L=3, alpha accumulated in step epilogue ----
  lstm_step<true,  false><<<6250, 256, 0, stream>>>(seq,                 hL, cL, Bf, bbf, attw,    alpha);
  lstm_step<false, false><<<6250, 256, 0, stream>>>(seq + (u64)NN2*64,   hL, cL, Bf, bbf, attw,    alpha + NN2);
  lstm_step<false, false><<<6250, 256, 0, stream>>>(seq + (u64)2*NN2*64, hL, cL, Bf, bbf, attw,    alpha + 2*NN2);
  lstm_step<true,  true ><<<6250, 256, 0, stream>>>(seq + (u64)2*NN2*64, hL, cL, Bb, bbb, attw+96, alpha + 2*NN2);
  lstm_step<false, true ><<<6250, 256, 0, stream>>>(seq + (u64)NN2*64,   hL, cL, Bb, bbb, attw+96, alpha + NN2);
  lstm_step<false, true ><<<6250, 256, 0, stream>>>(seq,                 hL, cL, Bb, bbb, attw+96, alpha);

  // ---- JK attention + heads ----
  alpha_softmax<<<782, 256, 0, stream>>>(alpha, attb);
  jk_kernel<<<12500, 256, 0, stream>>>(alpha, seq, jkout);
  node1_kernel<64, 2, false><<<dim3(3125,1), 256, 0, stream>>>(nullptr, jkout, nullptr, 0,
                                                               jkw, jkb, tmp2, nullptr, NN2);
  phi_sum<<<6250, 256, 0, stream>>>(tmp2, phi);                                // phi(x)+phi(-x)
  hipMemsetAsync(stats, 0, 256*sizeof(float), stream);
  node1_kernel<64, 2, true><<<dim3(1563,1), 256, 0, stream>>>(nullptr, phi, nullptr, 0,
                                                              rw1, rb1, tmp2, stats, NND);
  bn_finalize<<<1, 128, 0, stream>>>(stats, 1, 1.0f/NND);
  node2_kernel<false><<<dim3(1563,1), 256, 0, stream>>>(tmp2, stats, rg_, rbe, rw2, rb2, outp, NND);
}

// Round 12
// 3713.642 us; speedup vs baseline: 1.3128x; 1.3128x over previous
//
#include <hip/hip_runtime.h>
#include <math.h>

#define NND 100000      // nodes per phi
#define NE  1250000     // edges
#define NN2 200000      // 2N (pos+neg batched)
#define BNE 1e-5f

typedef unsigned long long u64;

// ---------------- workspace layout (float offsets) ----------------
// seq is live for the whole pipeline. Union U (38.4M floats):
//   conv : agg = U+0 (12.8M)  tmp1 = U+12.8M (12.8M)  CSR ints = U+25.6M (~1.45M)
//   lstm : hL  = U+0 (19.2M)  cL   = U+19.2M (19.2M)
//   jk   : jkout=U+0 (12.8M)  tmp2 = U+12.8M (12.8M)  phi = U+25.6M (6.4M)
#define OFF_SEQ   0ull                    // 3 * NN2 * 64 = 38,400,000
#define OFF_U     38400000ull             // union: 38,400,000 floats
#define OFF_ALPHA 76800000ull             // 3 * NN2 = 600,000
#define OFF_STATS 77400000ull             // 512
#define OFF_BF    77400512ull             // 160*384
#define OFF_BB    77461952ull             // 160*384
#define OFF_BBF   77523392ull             // 384
#define OFF_BBB   77523776ull             // 384
#define WS_FLOATS 77524160ull             // ~310.1 MB

__device__ __forceinline__ float fsig(float x)  { return 1.f/(1.f + __expf(-x)); }
__device__ __forceinline__ float ftanh(float x) { return 1.f - 2.f/(__expf(2.f*x) + 1.f); }

__device__ __forceinline__ void fma16(float (&acc)[4][4], const float4 a, const float4 b) {
  acc[0][0]=fmaf(a.x,b.x,acc[0][0]); acc[0][1]=fmaf(a.x,b.y,acc[0][1]);
  acc[0][2]=fmaf(a.x,b.z,acc[0][2]); acc[0][3]=fmaf(a.x,b.w,acc[0][3]);
  acc[1][0]=fmaf(a.y,b.x,acc[1][0]); acc[1][1]=fmaf(a.y,b.y,acc[1][1]);
  acc[1][2]=fmaf(a.y,b.z,acc[1][2]); acc[1][3]=fmaf(a.y,b.w,acc[1][3]);
  acc[2][0]=fmaf(a.z,b.x,acc[2][0]); acc[2][1]=fmaf(a.z,b.y,acc[2][1]);
  acc[2][2]=fmaf(a.z,b.z,acc[2][2]); acc[2][3]=fmaf(a.z,b.w,acc[2][3]);
  acc[3][0]=fmaf(a.w,b.x,acc[3][0]); acc[3][1]=fmaf(a.w,b.y,acc[3][1]);
  acc[3][2]=fmaf(a.w,b.z,acc[3][2]); acc[3][3]=fmaf(a.w,b.w,acc[3][3]);
}

// ================= CSR build (dst -> edge list), once per call =================
__global__ void hist_kernel(const int* __restrict__ dstp, int* __restrict__ cnt) {
  int e = blockIdx.x*256 + threadIdx.x;
  if (e < NE) atomicAdd(&cnt[dstp[e]], 1);
}

#define SCAN_B 1024
__global__ void scan1_kernel(const int* __restrict__ cnt, int* __restrict__ ofs,
                             int* __restrict__ bsum, int n) {
  __shared__ int lds[SCAN_B];
  int tid = threadIdx.x;
  int gid = blockIdx.x*SCAN_B + tid;
  int v = (gid < n) ? cnt[gid] : 0;
  lds[tid] = v;
  __syncthreads();
  for (int s = 1; s < SCAN_B; s <<= 1) {
    int t = (tid >= s) ? lds[tid - s] : 0;
    __syncthreads();
    lds[tid] += t;
    __syncthreads();
  }
  if (gid < n) ofs[gid] = lds[tid] - v;
  if (tid == SCAN_B-1) bsum[blockIdx.x] = lds[tid];
}

__global__ void scan2_kernel(int* __restrict__ bsum, int nb) {
  __shared__ int lds[128];
  int tid = threadIdx.x;
  int v = (tid < nb) ? bsum[tid] : 0;
  lds[tid] = v;
  __syncthreads();
  for (int s = 1; s < 128; s <<= 1) {
    int t = (tid >= s) ? lds[tid - s] : 0;
    __syncthreads();
    lds[tid] += t;
    __syncthreads();
  }
  if (tid < nb) bsum[tid] = lds[tid] - v;
}

__global__ void scan3_kernel(int* __restrict__ ofs, const int* __restrict__ bsum,
                             int* __restrict__ cur, int n) {
  int gid = blockIdx.x*SCAN_B + threadIdx.x;
  if (gid < n) {
    int o = ofs[gid] + bsum[blockIdx.x];
    ofs[gid] = o;
    cur[gid] = o;
  }
  if (gid == 0) ofs[n] = NE;
}

__global__ void fill_kernel(const int* __restrict__ dstp, int* __restrict__ cur,
                            int* __restrict__ eidl) {
  int e = blockIdx.x*256 + threadIdx.x;
  if (e < NE) {
    int p = atomicAdd(&cur[dstp[e]], 1);
    eidl[p] = e;
  }
}

// ========== gather aggregation: agg[n] = sum_{e: dst=n} relu(h[src]+emb(e)) ==========
template<int C, bool L0>
__global__ __launch_bounds__(256) void gather_kernel(
    const float* __restrict__ ea, const int* __restrict__ srcp,
    const int* __restrict__ ofs, const int* __restrict__ eidl,
    const float* __restrict__ lew, const float* __restrict__ leb,
    const float* __restrict__ hin, float* __restrict__ agg)
{
  __shared__ float sW[17*C];
  for (int i = threadIdx.x; i < 17*C; i += 256)
    sW[i] = (i < 16*C) ? lew[i] : leb[i - 16*C];
  __syncthreads();
  int lane = threadIdx.x & (C - 1);
  int grp  = threadIdx.x / C;
  int node = blockIdx.x*(256/C) + grp;
  if (node >= NND) return;
  int st = ofs[node], en = ofs[node+1];
  float accp = 0.f, accn = 0.f;
  int eid = 0, s = 0;
  if (st < en) { eid = eidl[st]; s = srcp[eid]; }
  for (int i = st; i < en; i++) {
    int neid = 0, ns = 0;
    if (i + 1 < en) { neid = eidl[i+1]; ns = srcp[neid]; }
    const float4* ea4 = reinterpret_cast<const float4*>(ea + (u64)eid*16);
    float emb = sW[16*C + lane];
    #pragma unroll
    for (int k4 = 0; k4 < 4; k4++) {
      float4 v = ea4[k4];
      emb = fmaf(v.x, sW[(4*k4+0)*C+lane], emb);
      emb = fmaf(v.y, sW[(4*k4+1)*C+lane], emb);
      emb = fmaf(v.z, sW[(4*k4+2)*C+lane], emb);
      emb = fmaf(v.w, sW[(4*k4+3)*C+lane], emb);
    }
    float hp, hn;
    if (L0) { hp = hin[(u64)s*C + lane]; hn = -hp; }
    else    { hp = hin[(u64)s*C + lane]; hn = hin[(u64)(NND + s)*C + lane]; }
    accp += fmaxf(hp + emb, 0.f);
    accn += fmaxf(hn + emb, 0.f);
    eid = neid; s = ns;
  }
  agg[(u64)node*C + lane]        = accp;
  agg[(u64)(NND + node)*C + lane] = accn;
}

// ------------- node GEMM 1: tmp1 = (agg + (1+eps)h) @ W + b ; optional BN partial stats ----
template<int CIN, int MODE, bool STATS>
__global__ __launch_bounds__(256) void node1_kernel(
    const float* __restrict__ agg, const float* __restrict__ hin,
    const float* __restrict__ epsp, int layer,
    const float* __restrict__ W, const float* __restrict__ bias,
    float* __restrict__ outp, float* __restrict__ stats, int rps)
{
  __shared__ __align__(16) float At[CIN][68];
  __shared__ __align__(16) float Bs[CIN][64];
  __shared__ float red[16][64];
  int tid = threadIdx.x;
  int sgn = blockIdx.y;
  int rowbase = blockIdx.x*64;
  for (int i = tid; i < CIN*64; i += 256) Bs[i>>6][i&63] = W[i];
  float sc = 1.f;
  if (MODE < 2) sc = 1.f + epsp[layer];
  for (int i = tid; i < 64*CIN; i += 256) {
    int r = i / CIN, k = i % CIN;
    int row = rowbase + r;
    float v = 0.f;
    if (row < rps) {
      int grow = sgn*rps + row;
      if (MODE == 0)      { float xv = hin[(u64)row*CIN + k]; v = agg[(u64)grow*CIN + k] + sc*(sgn ? -xv : xv); }
      else if (MODE == 1) { v = agg[(u64)grow*CIN + k] + sc*hin[(u64)grow*CIN + k]; }
      else                { v = hin[(u64)grow*64 + k]; }
    }
    At[k][r] = v;
  }
  __syncthreads();
  int rg = tid >> 4, cg = tid & 15;
  float acc[4][4] = {};
  // unroll capped: full unroll spilled (VGPR=256, scratch-bound, r2 post-mortem)
  #pragma unroll 4
  for (int k = 0; k < CIN; k++) {
    float4 a = *reinterpret_cast<const float4*>(&At[k][rg*4]);
    float4 b = *reinterpret_cast<const float4*>(&Bs[k][cg*4]);
    fma16(acc, a, b);
  }
  float bv[4];
  #pragma unroll
  for (int c = 0; c < 4; c++) bv[c] = bias[cg*4 + c];
  #pragma unroll
  for (int i = 0; i < 4; i++) {
    int row = rowbase + rg*4 + i;
    if (row < rps) {
      int grow = sgn*rps + row;
      float4 o4 = make_float4(acc[i][0]+bv[0], acc[i][1]+bv[1], acc[i][2]+bv[2], acc[i][3]+bv[3]);
      *reinterpret_cast<float4*>(&outp[(u64)grow*64 + cg*4]) = o4;
    }
  }
  if constexpr (STATS) {
    float sm[4] = {0,0,0,0}, sq[4] = {0,0,0,0};
    #pragma unroll
    for (int i = 0; i < 4; i++) {
      int row = rowbase + rg*4 + i;
      if (row < rps) {
        #pragma unroll
        for (int c = 0; c < 4; c++) { float t = acc[i][c] + bv[c]; sm[c] += t; sq[c] += t*t; }
      }
    }
    __syncthreads();
    #pragma unroll
    for (int c = 0; c < 4; c++) red[rg][cg*4+c] = sm[c];
    __syncthreads();
    for (int st = 8; st >= 1; st >>= 1) {
      if (rg < st) {
        #pragma unroll
        for (int c = 0; c < 4; c++) red[rg][cg*4+c] += red[rg+st][cg*4+c];
      }
      __syncthreads();
    }
    if (rg == 0) {
      #pragma unroll
      for (int c = 0; c < 4; c++) atomicAdd(&stats[sgn*64 + cg*4 + c], red[0][cg*4+c]);
    }
    __syncthreads();
    #pragma unroll
    for (int c = 0; c < 4; c++) red[rg][cg*4+c] = sq[c];
    __syncthreads();
    for (int st = 8; st >= 1; st >>= 1) {
      if (rg < st) {
        #pragma unroll
        for (int c = 0; c < 4; c++) red[rg][cg*4+c] += red[rg+st][cg*4+c];
      }
      __syncthreads();
    }
    if (rg == 0) {
      #pragma unroll
      for (int c = 0; c < 4; c++) atomicAdd(&stats[128 + sgn*64 + cg*4 + c], red[0][cg*4+c]);
    }
  }
}

__global__ void bn_finalize(float* stats, int nsign, float invN) {
  int i = threadIdx.x;
  if (i < nsign*64) {
    float mean = stats[i]*invN;
    float var  = stats[128+i]*invN - mean*mean;
    stats[256+i] = mean;
    stats[384+i] = rsqrtf(fmaxf(var, 0.f) + BNE);
  }
}

// ------------- node GEMM 2: out = [relu]( relu(bn(tmp1)) @ W + b ) -------------
template<bool TRELU>
__global__ __launch_bounds__(256) void node2_kernel(
    const float* __restrict__ tin, const float* __restrict__ stats,
    const float* __restrict__ gam, const float* __restrict__ bet,
    const float* __restrict__ W, const float* __restrict__ bias,
    float* __restrict__ outp, int rps)
{
  __shared__ __align__(16) float At[64][68];
  __shared__ __align__(16) float Bs[64][64];
  __shared__ float scs[64], shs[64];
  int tid = threadIdx.x;
  int sgn = blockIdx.y;
  int rowbase = blockIdx.x*64;
  if (tid < 64) {
    float mean = stats[256 + sgn*64 + tid];
    float istd = stats[384 + sgn*64 + tid];
    float s = istd * gam[tid];
    scs[tid] = s;
    shs[tid] = bet[tid] - mean*s;
  }
  for (int i = tid; i < 64*64; i += 256) Bs[i>>6][i&63] = W[i];
  __syncthreads();
  for (int i = tid; i < 64*64; i += 256) {
    int r = i >> 6, k = i & 63;
    int row = rowbase + r;
    float v = 0.f;
    if (row < rps) {
      int grow = sgn*rps + row;
      v = fmaxf(fmaf(tin[(u64)grow*64 + k], scs[k], shs[k]), 0.f);
    }
    At[k][r] = v;
  }
  __syncthreads();
  int rg = tid >> 4, cg = tid & 15;
  float acc[4][4] = {};
  #pragma unroll 4
  for (int k = 0; k < 64; k++) {
    float4 a = *reinterpret_cast<const float4*>(&At[k][rg*4]);
    float4 b = *reinterpret_cast<const float4*>(&Bs[k][cg*4]);
    fma16(acc, a, b);
  }
  #pragma unroll
  for (int i = 0; i < 4; i++) {
    int row = rowbase + rg*4 + i;
    if (row < rps) {
      int grow = sgn*rps + row;
      float o0 = acc[i][0] + bias[cg*4+0];
      float o1 = acc[i][1] + bias[cg*4+1];
      float o2 = acc[i][2] + bias[cg*4+2];
      float o3 = acc[i][3] + bias[cg*4+3];
      if (TRELU) { o0=fmaxf(o0,0.f); o1=fmaxf(o1,0.f); o2=fmaxf(o2,0.f); o3=fmaxf(o3,0.f); }
      *reinterpret_cast<float4*>(&outp[(u64)grow*64 + cg*4]) = make_float4(o0,o1,o2,o3);
    }
  }
}

// ------------- LSTM weight prep: B[k][u*4+g] = W[g*96+u][k] (gate-interleaved) -------------
__global__ void prep_lstm_w(
    const float* __restrict__ wif, const float* __restrict__ whf,
    const float* __restrict__ bif, const float* __restrict__ bhf,
    const float* __restrict__ wib, const float* __restrict__ whb,
    const float* __restrict__ bib, const float* __restrict__ bhb,
    float* __restrict__ Bf, float* __restrict__ Bb,
    float* __restrict__ bbf, float* __restrict__ bbb)
{
  int idx = blockIdx.x*256 + threadIdx.x;
  if (idx >= 2*160*384) return;
  int d = idx / (160*384);
  int rem = idx - d*160*384;
  int k = rem / 384, ju = rem - k*384;
  int u = ju >> 2, g = ju & 3;
  int grow = g*96 + u;              // torch gate order i,f,g,o
  const float* wi = d ? wib : wif;
  const float* wh = d ? whb : whf;
  float* Bo = d ? Bb : Bf;
  Bo[rem] = (k < 64) ? wi[grow*64 + k] : wh[grow*96 + (k - 64)];
  if (k == 0) {
    const float* bi = d ? bib : bif;
    const float* bh = d ? bhb : bhf;
    (d ? bbb : bbf)[ju] = bi[grow] + bh[grow];
  }
}

// ------------- fused LSTM step: gates GEMM + activations + alpha partial -------------
// r12: r7-proven structure (LDS-staged Bs — r11's direct-L2 read was VMEM-bound, 686us);
// Bs chunk 16->8 rows: LDS 47.6->35.3KB -> 4 blocks/CU (occupancy 33->~50%).
template<bool FIRST, bool ACC_ALPHA>
__global__ __launch_bounds__(256) void lstm_step(
    const float* __restrict__ xt, float* __restrict__ h, float* __restrict__ c,
    const float* __restrict__ B, const float* __restrict__ bb,
    const float* __restrict__ attw, float* __restrict__ alpha)
{
  constexpr int K = FIRST ? 64 : 160;
  __shared__ __align__(16) float At[160][36];
  __shared__ __align__(16) float Bs[8][384];
  int tid = threadIdx.x;
  int rowbase = blockIdx.x * 32;
  // division-free float4 staging: 8 threads per row
  {
    int r = tid >> 3, t8 = tid & 7;
    u64 grow = (u64)(rowbase + r);
    float4 v0 = *reinterpret_cast<const float4*>(&xt[grow*64 + t8*8]);
    float4 v1 = *reinterpret_cast<const float4*>(&xt[grow*64 + t8*8 + 4]);
    int kx = t8*8;
    At[kx+0][r] = v0.x; At[kx+1][r] = v0.y; At[kx+2][r] = v0.z; At[kx+3][r] = v0.w;
    At[kx+4][r] = v1.x; At[kx+5][r] = v1.y; At[kx+6][r] = v1.z; At[kx+7][r] = v1.w;
    if (!FIRST) {
      float4 h0 = *reinterpret_cast<const float4*>(&h[grow*96 + t8*12]);
      float4 h1 = *reinterpret_cast<const float4*>(&h[grow*96 + t8*12 + 4]);
      float4 h2 = *reinterpret_cast<const float4*>(&h[grow*96 + t8*12 + 8]);
      int kh = 64 + t8*12;
      At[kh+0][r] = h0.x; At[kh+1][r]  = h0.y; At[kh+2][r]  = h0.z; At[kh+3][r]  = h0.w;
      At[kh+4][r] = h1.x; At[kh+5][r]  = h1.y; At[kh+6][r]  = h1.z; At[kh+7][r]  = h1.w;
      At[kh+8][r] = h2.x; At[kh+9][r]  = h2.y; At[kh+10][r] = h2.z; At[kh+11][r] = h2.w;
    }
  }
  float acc[4][3][4] = {};
  int rg = tid >> 5, tc = tid & 31;
  for (int kc = 0; kc < K/8; kc++) {
    __syncthreads();
    const float4* bsrc = reinterpret_cast<const float4*>(B + kc*8*384);
    float4* bdst = reinterpret_cast<float4*>(&Bs[0][0]);
    for (int i = tid; i < 768; i += 256) bdst[i] = bsrc[i];
    __syncthreads();
    // unroll capped to avoid VGPR spill (r2 post-mortem)
    #pragma unroll 4
    for (int k = 0; k < 8; k++) {
      float4 a = *reinterpret_cast<const float4*>(&At[kc*8+k][rg*4]);
      #pragma unroll
      for (int uu = 0; uu < 3; uu++) {
        float4 b = *reinterpret_cast<const float4*>(&Bs[k][(uu*32+tc)*4]);
        acc[0][uu][0]=fmaf(a.x,b.x,acc[0][uu][0]); acc[0][uu][1]=fmaf(a.x,b.y,acc[0][uu][1]);
        acc[0][uu][2]=fmaf(a.x,b.z,acc[0][uu][2]); acc[0][uu][3]=fmaf(a.x,b.w,acc[0][uu][3]);
        acc[1][uu][0]=fmaf(a.y,b.x,acc[1][uu][0]); acc[1][uu][1]=fmaf(a.y,b.y,acc[1][uu][1]);
        acc[1][uu][2]=fmaf(a.y,b.z,acc[1][uu][2]); acc[1][uu][3]=fmaf(a.y,b.w,acc[1][uu][3]);
        acc[2][uu][0]=fmaf(a.z,b.x,acc[2][uu][0]); acc[2][uu][1]=fmaf(a.z,b.y,acc[2][uu][1]);
        acc[2][uu][2]=fmaf(a.z,b.z,acc[2][uu][2]); acc[2][uu][3]=fmaf(a.z,b.w,acc[2][uu][3]);
        acc[3][uu][0]=fmaf(a.w,b.x,acc[3][uu][0]); acc[3][uu][1]=fmaf(a.w,b.y,acc[3][uu][1]);
        acc[3][uu][2]=fmaf(a.w,b.z,acc[3][uu][2]); acc[3][uu][3]=fmaf(a.w,b.w,acc[3][uu][3]);
      }
    }
  }
  float aw[3], bbv[3][4];
  #pragma unroll
  for (int uu = 0; uu < 3; uu++) {
    int u = uu*32 + tc;
    aw[uu] = attw[u];
    #pragma unroll
    for (int g2 = 0; g2 < 4; g2++) bbv[uu][g2] = bb[u*4 + g2];
  }
  float apart[4];
  #pragma unroll
  for (int r = 0; r < 4; r++) {
    int row = rowbase + rg*4 + r;
    float ap = 0.f;
    #pragma unroll
    for (int uu = 0; uu < 3; uu++) {
      int u = uu*32 + tc;
      float gi = acc[r][uu][0] + bbv[uu][0];
      float gf = acc[r][uu][1] + bbv[uu][1];
      float gg = acc[r][uu][2] + bbv[uu][2];
      float go = acc[r][uu][3] + bbv[uu][3];
      float si = fsig(gi);
      float sf = fsig(gf);
      float so = fsig(go);
      float tg = ftanh(gg);
      float cp = FIRST ? 0.f : c[(u64)row*96 + u];
      float cn = fmaf(sf, cp, si*tg);
      float hn = so * ftanh(cn);
      c[(u64)row*96 + u] = cn;
      h[(u64)row*96 + u] = hn;
      ap = fmaf(hn, aw[uu], ap);
    }
    apart[r] = ap;
  }
  #pragma unroll
  for (int m = 16; m >= 1; m >>= 1) {
    #pragma unroll
    for (int r = 0; r < 4; r++) apart[r] += __shfl_xor(apart[r], m, 32);
  }
  if (tc == 0) {
    #pragma unroll
    for (int r = 0; r < 4; r++) {
      int row = rowbase + rg*4 + r;
      float v = apart[r];
      if (ACC_ALPHA) v += alpha[row];
      alpha[row] = v;
    }
  }
}

__global__ void alpha_softmax(float* alpha, const float* __restrict__ attb) {
  int row = blockIdx.x*256 + threadIdx.x;
  if (row >= NN2) return;
  float b = attb[0];
  float a0 = alpha[row] + b, a1 = alpha[NN2+row] + b, a2 = alpha[2*NN2+row] + b;
  float m = fmaxf(a0, fmaxf(a1, a2));
  float e0 = expf(a0-m), e1 = expf(a1-m), e2 = expf(a2-m);
  float inv = 1.f/(e0+e1+e2);
  alpha[row] = e0*inv; alpha[NN2+row] = e1*inv; alpha[2*NN2+row] = e2*inv;
}

__global__ void jk_kernel(const float* __restrict__ alpha, const float* __restrict__ seq,
                          float* __restrict__ outp) {
  int idx = blockIdx.x*256 + threadIdx.x;   // NN2*16
  if (idx >= NN2*16) return;
  int row = idx >> 4, c4 = idx & 15;
  float a0 = alpha[row], a1 = alpha[NN2+row], a2 = alpha[2*NN2+row];
  float4 s0 = *reinterpret_cast<const float4*>(&seq[((u64)0*NN2 + row)*64 + c4*4]);
  float4 s1 = *reinterpret_cast<const float4*>(&seq[((u64)1*NN2 + row)*64 + c4*4]);
  float4 s2 = *reinterpret_cast<const float4*>(&seq[((u64)2*NN2 + row)*64 + c4*4]);
  float4 o;
  o.x = a0*s0.x + a1*s1.x + a2*s2.x;
  o.y = a0*s0.y + a1*s1.y + a2*s2.y;
  o.z = a0*s0.z + a1*s1.z + a2*s2.z;
  o.w = a0*s0.w + a1*s1.w + a2*s2.w;
  *reinterpret_cast<float4*>(&outp[(u64)row*64 + c4*4]) = o;
}

__global__ void phi_sum(const float* __restrict__ t, float* __restrict__ o) {
  int idx = blockIdx.x*256 + threadIdx.x;   // NND*16
  if (idx >= NND*16) return;
  float4 a = reinterpret_cast<const float4*>(t)[idx];
  float4 b = reinterpret_cast<const float4*>(t + (u64)NND*64)[idx];
  reinterpret_cast<float4*>(o)[idx] = make_float4(a.x+b.x, a.y+b.y, a.z+b.z, a.w+b.w);
}

extern "C" void kernel_launch(void* const* d_in, const int* in_sizes, int n_in,
                              void* d_out, int out_size, void* d_ws, size_t ws_size,
                              hipStream_t stream) {
  const float* x    = (const float*)d_in[0];
  const int*   ei   = (const int*)d_in[1];
  const int*   srcp = ei;
  const int*   dstp = ei + NE;
  const float* ea   = (const float*)d_in[2];
  const float* lew[3] = {(const float*)d_in[3],  (const float*)d_in[11], (const float*)d_in[19]};
  const float* leb[3] = {(const float*)d_in[4],  (const float*)d_in[12], (const float*)d_in[20]};
  const float* w1[3]  = {(const float*)d_in[5],  (const float*)d_in[13], (const float*)d_in[21]};
  const float* b1[3]  = {(const float*)d_in[6],  (const float*)d_in[14], (const float*)d_in[22]};
  const float* gg[3]  = {(const float*)d_in[7],  (const float*)d_in[15], (const float*)d_in[23]};
  const float* be[3]  = {(const float*)d_in[8],  (const float*)d_in[16], (const float*)d_in[24]};
  const float* w2[3]  = {(const float*)d_in[9],  (const float*)d_in[17], (const float*)d_in[25]};
  const float* b2[3]  = {(const float*)d_in[10], (const float*)d_in[18], (const float*)d_in[26]};
  const float* eps  = (const float*)d_in[27];
  const float* wif  = (const float*)d_in[28];
  const float* whf  = (const float*)d_in[29];
  const float* bif  = (const float*)d_in[30];
  const float* bhf  = (const float*)d_in[31];
  const float* wib  = (const float*)d_in[32];
  const float* whb  = (const float*)d_in[33];
  const float* bib  = (const float*)d_in[34];
  const float* bhb  = (const float*)d_in[35];
  const float* attw = (const float*)d_in[36];
  const float* attb = (const float*)d_in[37];
  const float* jkw  = (const float*)d_in[38];
  const float* jkb  = (const float*)d_in[39];
  const float* rw1  = (const float*)d_in[40];
  const float* rb1  = (const float*)d_in[41];
  const float* rg_  = (const float*)d_in[42];
  const float* rbe  = (const float*)d_in[43];
  const float* rw2  = (const float*)d_in[44];
  const float* rb2  = (const float*)d_in[45];

  float* ws    = (float*)d_ws;
  float* seq   = ws + OFF_SEQ;
  float* U     = ws + OFF_U;
  float* agg   = U;                       // conv phase
  float* tmp1  = U + 12800000ull;         // conv phase
  float* hL    = U;                       // lstm phase
  float* cL    = U + 19200000ull;         // lstm phase
  float* jkout = U;                       // jk phase
  float* tmp2  = U + 12800000ull;         // jk phase
  float* phi   = U + 25600000ull;         // jk phase (NND*64)
  int* csr_ofs  = (int*)(U + 25600000ull);          // conv phase: NND+1
  int* csr_cur  = csr_ofs + (NND + 1);              // NND
  int* csr_bsum = csr_cur + NND;                    // 128
  int* csr_eidl = csr_bsum + 128;                   // NE
  float* alpha = ws + OFF_ALPHA;
  float* stats = ws + OFF_STATS;
  float* Bf    = ws + OFF_BF;
  float* Bb    = ws + OFF_BB;
  float* bbf   = ws + OFF_BBF;
  float* bbb   = ws + OFF_BBB;
  float* outp  = (float*)d_out;

  if (ws_size < WS_FLOATS * sizeof(float)) return;  // need ~310 MB scratch

  prep_lstm_w<<<480, 256, 0, stream>>>(wif, whf, bif, bhf, wib, whb, bib, bhb, Bf, Bb, bbf, bbb);

  // ---- build CSR (dst -> edges), once per call ----
  const int nscan = (NND + SCAN_B - 1) / SCAN_B;    // 98
  hipMemsetAsync(csr_cur, 0, NND*sizeof(int), stream);
  hist_kernel<<<(NE+255)/256, 256, 0, stream>>>(dstp, csr_cur);
  scan1_kernel<<<nscan, SCAN_B, 0, stream>>>(csr_cur, csr_ofs, csr_bsum, NND);
  scan2_kernel<<<1, 128, 0, stream>>>(csr_bsum, nscan);
  scan3_kernel<<<nscan, SCAN_B, 0, stream>>>(csr_ofs, csr_bsum, csr_cur, NND);
  fill_kernel<<<(NE+255)/256, 256, 0, stream>>>(dstp, csr_cur, csr_eidl);

  // ---- 3 GINE layers, both signs batched (2N rows), gather aggregation ----
  for (int l = 0; l < 3; l++) {
    const float* hin = (l == 0) ? x : (seq + (u64)(l-1)*NN2*64);
    if (l == 0)
      gather_kernel<16, true ><<<(NND+15)/16, 256, 0, stream>>>(ea, srcp, csr_ofs, csr_eidl,
                                                                lew[l], leb[l], hin, agg);
    else
      gather_kernel<64, false><<<(NND+3)/4, 256, 0, stream>>>(ea, srcp, csr_ofs, csr_eidl,
                                                              lew[l], leb[l], hin, agg);
    hipMemsetAsync(stats, 0, 256*sizeof(float), stream);
    dim3 g1(1563, 2);
    if (l == 0)
      node1_kernel<16, 0, true><<<g1, 256, 0, stream>>>(agg, x, eps, l, w1[l], b1[l], tmp1, stats, NND);
    else
      node1_kernel<64, 1, true><<<g1, 256, 0, stream>>>(agg, hin, eps, l, w1[l], b1[l], tmp1, stats, NND);
    bn_finalize<<<1, 128, 0, stream>>>(stats, 2, 1.0f/NND);
    node2_kernel<true><<<g1, 256, 0, stream>>>(tmp1, stats, gg[l], be[l], w2[l], b2[l],
                                               seq + (u64)l*NN2*64, NND);
  }

  // ---- BiLSTM over L=3, alpha accumulated in step epilogue ----
  lstm_step<true,  false><<<6250, 256, 0, stream>>>(seq,                 hL, cL, Bf, bbf, attw,    alpha);
  lstm_step<false, false><<<6250, 256, 0, stream>>>(seq + (u64)NN2*64,   hL, cL, Bf, bbf, attw,    alpha + NN2);
  lstm_step<false, false><<<6250, 256, 0, stream>>>(seq + (u64)2*NN2*64, hL, cL, Bf, bbf, attw,    alpha + 2*NN2);
  lstm_step<true,  true ><<<6250, 256, 0, stream>>>(seq + (u64)2*NN2*64, hL, cL, Bb, bbb, attw+96, alpha + 2*NN2);
  lstm_step<false, true ><<<6250, 256, 0, stream>>>(seq + (u64)NN2*64,   hL, cL, Bb, bbb, attw+96, alpha + NN2);
  lstm_step<false, true ><<<6250, 256, 0, stream>>>(seq,                 hL, cL, Bb, bbb, attw+96, alpha);

  // ---- JK attention + heads ----
  alpha_softmax<<<782, 256, 0, stream>>>(alpha, attb);
  jk_kernel<<<12500, 256, 0, stream>>>(alpha, seq, jkout);
  node1_kernel<64, 2, false><<<dim3(3125,1), 256, 0, stream>>>(nullptr, jkout, nullptr, 0,
                                                               jkw, jkb, tmp2, nullptr, NN2);
  phi_sum<<<6250, 256, 0, stream>>>(tmp2, phi);                                // phi(x)+phi(-x)
  hipMemsetAsync(stats, 0, 256*sizeof(float), stream);
  node1_kernel<64, 2, true><<<dim3(1563,1), 256, 0, stream>>>(nullptr, phi, nullptr, 0,
                                                              rw1, rb1, tmp2, stats, NND);
  bn_finalize<<<1, 128, 0, stream>>>(stats, 1, 1.0f/NND);
  node2_kernel<false><<<dim3(1563,1), 256, 0, stream>>>(tmp2, stats, rg_, rbe, rw2, rb2, outp, NND);
}